// Round 6
// baseline (307.265 us; speedup 1.0000x reference)
//
#include <hip/hip_runtime.h>
#include <hip/hip_bf16.h>

typedef unsigned short u16;
typedef unsigned int u32;
typedef __attribute__((ext_vector_type(8))) short short8;
typedef __attribute__((ext_vector_type(4))) float f32x4;
typedef __attribute__((ext_vector_type(4))) _Float16 f16x4;

// fp32 -> bf16 round-to-nearest-even (finite inputs only)
static __device__ __forceinline__ u16 f2b(float f) {
  unsigned u = __builtin_bit_cast(unsigned, f);
  unsigned r = u + 0x7fffu + ((u >> 16) & 1u);
  return (u16)(r >> 16);
}
static __device__ __forceinline__ unsigned pk2(float a, float b) {
  return (unsigned)f2b(a) | ((unsigned)f2b(b) << 16);
}
// two fp32 -> packed fp16 (RTZ pack instruction)
static __device__ __forceinline__ u32 pkh(float a, float b) {
  return __builtin_bit_cast(u32, __builtin_amdgcn_cvt_pkrtz(a, b));
}

// async 16B global -> LDS (wave-uniform LDS base + lane*16)
static __device__ __forceinline__ void gl_lds16(const u16* g, u16* l) {
  __builtin_amdgcn_global_load_lds(
      (const __attribute__((address_space(1))) unsigned*)g,
      (__attribute__((address_space(3))) unsigned*)l, 16, 0, 0);
}

// XOR-swizzle: LDS slot s=(r*8+cgs) holds global chunk (r, cgs^(r&7)).
// Spreads the 16 lr-rows of a ds_read_b128 across all 8 bank groups
// -> uniform depth-8 = the b128 floor. (r5: conflicts 1.9e7 -> 0)

// ---------------------------------------------------------------------------
// Prep (merged): bf16 transposed weights (coalesced WRITES, strided reads --
// w is 3 MB, L2 absorbs the read replay) + x fp32->bf16.
// ---------------------------------------------------------------------------
__global__ __launch_bounds__(256) void prep(
    const float* __restrict__ wq, const float* __restrict__ wk,
    const float* __restrict__ wv, const float* __restrict__ wo,
    const float* __restrict__ x, u16* __restrict__ wqkv_t,
    u16* __restrict__ wo_t, u16* __restrict__ xb) {
  int t = blockIdx.x * 256 + threadIdx.x;
  if (t < 786432) {
    int n = t >> 9, k = t & 511;  // write idx n*512+k, k fastest: coalesced
    const float* w = (n < 512) ? wq : (n < 1024 ? wk : wv);
    wqkv_t[(size_t)n * 512 + k] = f2b(w[k * 512 + (n & 511)]);
  } else if (t < 1048576) {
    int j = t - 786432;
    int n = j >> 9, k = j & 511;
    wo_t[(size_t)n * 512 + k] = f2b(wo[k * 512 + n]);
  } else {
    size_t i = (size_t)(t - 1048576) * 4;
    float4 v = *reinterpret_cast<const float4*>(&x[i]);
    uint2 p;
    p.x = pk2(v.x, v.y);
    p.y = pk2(v.z, v.w);
    *reinterpret_cast<uint2*>(&xb[i]) = p;
  }
}

// ---------------------------------------------------------------------------
// GEMM1: qkv[32768][1536] = xb[32768][512] @ wqkv_t^T + bias.
// Q cols pre-scaled by 0.125 (bf16), K cols bf16, V cols fp16.
// grid (12, 256): n fastest -> the 12 blocks sharing an A-tile run together.
// ---------------------------------------------------------------------------
__global__ __launch_bounds__(256, 4) void gemm_qkv(
    const u16* __restrict__ xb, const u16* __restrict__ wt,
    const float* __restrict__ bq, const float* __restrict__ bk,
    const float* __restrict__ bv, u16* __restrict__ qkv) {
  __shared__ u16 As[128 * 64];
  __shared__ u16 Bs[128 * 64];
  const int tid = threadIdx.x;
  const int wave = tid >> 6, lane = tid & 63;
  const int wm = wave & 1, wn = wave >> 1;
  const int lr = lane & 15, lg = lane >> 4;
  const int n0 = blockIdx.x * 128, m0 = blockIdx.y * 128;

  const f32x4 fz = {0.f, 0.f, 0.f, 0.f};
  f32x4 acc[4][4];
#pragma unroll
  for (int i = 0; i < 4; ++i)
#pragma unroll
    for (int j = 0; j < 4; ++j) acc[i][j] = fz;

  for (int kb = 0; kb < 512; kb += 64) {
#pragma unroll
    for (int j = 0; j < 4; ++j) {
      const int cb = (wave * 4 + j) * 64;
      const int c = cb + lane;
      const int r = c >> 3;
      const int cg = (c & 7) ^ (r & 7);  // XOR swizzle
      gl_lds16(&xb[(size_t)(m0 + r) * 512 + kb + (cg << 3)], &As[cb * 8]);
      gl_lds16(&wt[(size_t)(n0 + r) * 512 + kb + (cg << 3)], &Bs[cb * 8]);
    }
    __syncthreads();
#pragma unroll
    for (int ks = 0; ks < 2; ++ks) {
      short8 af[4], bb[4];
#pragma unroll
      for (int i = 0; i < 4; ++i)
        af[i] = *reinterpret_cast<const short8*>(
            &As[(wm * 64 + i * 16 + lr) * 64 +
                (((ks * 4 + lg) ^ (lr & 7)) << 3)]);
#pragma unroll
      for (int j = 0; j < 4; ++j)
        bb[j] = *reinterpret_cast<const short8*>(
            &Bs[(wn * 64 + j * 16 + lr) * 64 +
                (((ks * 4 + lg) ^ (lr & 7)) << 3)]);
#pragma unroll
      for (int i = 0; i < 4; ++i)
#pragma unroll
        for (int j = 0; j < 4; ++j)
          acc[i][j] = __builtin_amdgcn_mfma_f32_16x16x32_bf16(
              af[i], bb[j], acc[i][j], 0, 0, 0);
    }
    __syncthreads();
  }
#pragma unroll
  for (int i = 0; i < 4; ++i) {
    const int row0 = m0 + wm * 64 + i * 16 + lg * 4;
#pragma unroll
    for (int j = 0; j < 4; ++j) {
      const int col = n0 + wn * 64 + j * 16 + lr;
      const float bias =
          (col < 512) ? bq[col] : (col < 1024 ? bk[col - 512] : bv[col - 1024]);
#pragma unroll
      for (int r = 0; r < 4; ++r) {
        float v = acc[i][j][r] + bias;
        u16 ov;
        if (col < 512)
          ov = f2b(v * 0.125f);                       // Q: fold 1/sqrt(64)
        else if (col < 1024)
          ov = f2b(v);                                // K: bf16
        else
          ov = __builtin_bit_cast(u16, (_Float16)v);  // V: fp16
        qkv[(size_t)(row0 + r) * 1536 + col] = ov;
      }
    }
  }
}

// ---------------------------------------------------------------------------
// Flash attention. Block = (b, h, 128 q-rows), 4 waves x 32 q.
// S^T = K·Q^T (bf16 x32) -> exp in regs -> P^T in x16-f16 B-layout ->
// O^T = V^T·P^T (fp16 x16). K dbuf via global_load_lds (XOR-swizzled),
// V dbuf via register prefetch + transposed store (stride 70).
// ---------------------------------------------------------------------------
__global__ __launch_bounds__(256, 3) void attn(const u16* __restrict__ qkv,
                                               u16* __restrict__ ctx) {
  __shared__ u16 QOs[128 * 66];     // Q (swizzled stride 64) / O^T (stride 66)
  __shared__ u16 Ks[2][64 * 64];    // bf16, async, XOR-swizzled
  __shared__ u16 VsT[2][64 * 70];   // fp16, VsT[d][t], stride 70

  const int tid = threadIdx.x;
  const int wave = tid >> 6, lane = tid & 63;
  const int lr = lane & 15, lg = lane >> 4;
  const int bx = blockIdx.x;
  const int q0 = (bx & 3) * 128;
  const int h = (bx >> 2) & 7;
  const int b = bx >> 5;
  const size_t rowbase = (size_t)b * 512;

  // async-load Q tile (128 x 64, swizzled)
#pragma unroll
  for (int j = 0; j < 4; ++j) {
    const int cb = (wave * 4 + j) * 64, c = cb + lane;
    const int r = c >> 3, cg = (c & 7) ^ (r & 7);
    gl_lds16(&qkv[(rowbase + q0 + r) * 1536 + h * 64 + (cg << 3)],
             &QOs[cb * 8]);
  }
  // async-load K tile 0 (swizzled)
#pragma unroll
  for (int j = 0; j < 2; ++j) {
    const int cb = (wave * 2 + j) * 64, c = cb + lane;
    const int r = c >> 3, cg = (c & 7) ^ (r & 7);
    gl_lds16(&qkv[(rowbase + r) * 1536 + 512 + h * 64 + (cg << 3)],
             &Ks[0][cb * 8]);
  }
  // V tile 0: regs -> transposed LDS
  uint4 vreg[2];
#pragma unroll
  for (int i = 0; i < 2; ++i) {
    int idx = tid + i * 256, r = idx >> 3, cg = idx & 7;
    vreg[i] = *reinterpret_cast<const uint4*>(
        &qkv[(rowbase + r) * 1536 + 1024 + h * 64 + cg * 8]);
  }
#pragma unroll
  for (int i = 0; i < 2; ++i) {
    int idx = tid + i * 256, r = idx >> 3, cg = idx & 7;
    const u16* pv = reinterpret_cast<const u16*>(&vreg[i]);
#pragma unroll
    for (int jj = 0; jj < 8; ++jj) VsT[0][(cg * 8 + jj) * 70 + r] = pv[jj];
  }
  __syncthreads();

  // Q fragments (B-operand of S^T mfma); QOs dead until epilogue
  short8 aq[2][2];
#pragma unroll
  for (int g = 0; g < 2; ++g)
#pragma unroll
    for (int ks = 0; ks < 2; ++ks)
      aq[g][ks] = *reinterpret_cast<const short8*>(
          &QOs[(wave * 32 + g * 16 + lr) * 64 +
               (((ks * 4 + lg) ^ (lr & 7)) << 3)]);

  const f32x4 fz = {0.f, 0.f, 0.f, 0.f};
  f32x4 oacc[2][4];
#pragma unroll
  for (int g = 0; g < 2; ++g)
#pragma unroll
    for (int dt = 0; dt < 4; ++dt) oacc[g][dt] = fz;
  float lsum[2] = {0.f, 0.f};

  for (int tt = 0; tt < 8; ++tt) {
    const int buf = tt & 1;
    if (tt < 7) {  // prefetch K/V for tile tt+1
#pragma unroll
      for (int j = 0; j < 2; ++j) {
        const int cb = (wave * 2 + j) * 64, c = cb + lane;
        const int r = c >> 3, cg = (c & 7) ^ (r & 7);
        gl_lds16(&qkv[(rowbase + (tt + 1) * 64 + r) * 1536 + 512 + h * 64 +
                      (cg << 3)],
                 &Ks[buf ^ 1][cb * 8]);
      }
#pragma unroll
      for (int i = 0; i < 2; ++i) {
        int idx = tid + i * 256, r = idx >> 3, cg = idx & 7;
        vreg[i] = *reinterpret_cast<const uint4*>(
            &qkv[(rowbase + (tt + 1) * 64 + r) * 1536 + 1024 + h * 64 + cg * 8]);
      }
    }

    // S^T = K·Q^T : st[g][mt] covers t = mt*16+lg*4+r, q = lr
    f32x4 st[2][4];
#pragma unroll
    for (int g = 0; g < 2; ++g)
#pragma unroll
      for (int mt = 0; mt < 4; ++mt) st[g][mt] = fz;
#pragma unroll
    for (int mt = 0; mt < 4; ++mt) {
      short8 k0 = *reinterpret_cast<const short8*>(
          &Ks[buf][(mt * 16 + lr) * 64 + ((lg ^ (lr & 7)) << 3)]);
      short8 k1 = *reinterpret_cast<const short8*>(
          &Ks[buf][(mt * 16 + lr) * 64 + (((4 + lg) ^ (lr & 7)) << 3)]);
#pragma unroll
      for (int g = 0; g < 2; ++g) {
        st[g][mt] = __builtin_amdgcn_mfma_f32_16x16x32_bf16(k0, aq[g][0],
                                                            st[g][mt], 0, 0, 0);
        st[g][mt] = __builtin_amdgcn_mfma_f32_16x16x32_bf16(k1, aq[g][1],
                                                            st[g][mt], 0, 0, 0);
      }
    }

    // exp (Q pre-scaled), partial l, pack P^T straight into x16 B-layout
    f16x4 pfrag[2][4];
#pragma unroll
    for (int g = 0; g < 2; ++g)
#pragma unroll
      for (int mt = 0; mt < 4; ++mt) {
        float e0 = __expf(st[g][mt][0]), e1 = __expf(st[g][mt][1]);
        float e2 = __expf(st[g][mt][2]), e3 = __expf(st[g][mt][3]);
        lsum[g] += (e0 + e1) + (e2 + e3);
        uint2 uu;
        uu.x = pkh(e0, e1);
        uu.y = pkh(e2, e3);
        pfrag[g][mt] = __builtin_bit_cast(f16x4, uu);
      }

    // O^T += V^T · P^T  (x16 f16 MFMA; A-frag from VsT, B-frag = pfrag)
#pragma unroll
    for (int dt = 0; dt < 4; ++dt) {
#pragma unroll
      for (int tw = 0; tw < 4; ++tw) {
        const int a0 = (dt * 16 + lr) * 70 + tw * 16 + lg * 4;
        uint2 uu;
        uu.x = *reinterpret_cast<const u32*>(&VsT[buf][a0]);
        uu.y = *reinterpret_cast<const u32*>(&VsT[buf][a0 + 2]);
        f16x4 vf = __builtin_bit_cast(f16x4, uu);
#pragma unroll
        for (int g = 0; g < 2; ++g)
          oacc[g][dt] = __builtin_amdgcn_mfma_f32_16x16x16f16(
              vf, pfrag[g][tw], oacc[g][dt], 0, 0, 0);
      }
    }

    if (tt < 7) {  // write prefetched V^T into the other buffer
#pragma unroll
      for (int i = 0; i < 2; ++i) {
        int idx = tid + i * 256, r = idx >> 3, cg = idx & 7;
        const u16* pv = reinterpret_cast<const u16*>(&vreg[i]);
#pragma unroll
        for (int jj = 0; jj < 8; ++jj)
          VsT[buf ^ 1][(cg * 8 + jj) * 70 + r] = pv[jj];
      }
    }
    __syncthreads();
  }

  // reduce l over the 4 lane-groups holding each q, normalize
#pragma unroll
  for (int g = 0; g < 2; ++g) {
    float s = lsum[g];
    s += __shfl_xor(s, 16);
    s += __shfl_xor(s, 32);
    lsum[g] = 1.0f / s;
  }
  // O^T -> O via LDS (u32-granular, stride 66), then coalesced stores
#pragma unroll
  for (int g = 0; g < 2; ++g)
#pragma unroll
    for (int dt = 0; dt < 4; ++dt) {
      f32x4 o = oacc[g][dt];
      const float li = lsum[g];
      const int base = (wave * 32 + g * 16 + lr) * 66 + dt * 16 + lg * 4;
      *reinterpret_cast<u32*>(&QOs[base]) = pk2(o[0] * li, o[1] * li);
      *reinterpret_cast<u32*>(&QOs[base + 2]) = pk2(o[2] * li, o[3] * li);
    }
  __syncthreads();
  const size_t coff = (rowbase + q0) * 512 + h * 64;
#pragma unroll
  for (int i = 0; i < 4; ++i) {
    int idx = tid + i * 256, r = idx >> 3, cg = idx & 7;
    const u16* src = &QOs[r * 66 + cg * 8];
    uint4 w;
    w.x = *reinterpret_cast<const u32*>(&src[0]);
    w.y = *reinterpret_cast<const u32*>(&src[2]);
    w.z = *reinterpret_cast<const u32*>(&src[4]);
    w.w = *reinterpret_cast<const u32*>(&src[6]);
    *reinterpret_cast<uint4*>(&ctx[coff + (size_t)r * 512 + cg * 8]) = w;
  }
}

// ---------------------------------------------------------------------------
// GEMM2: out[32768][512] fp32 = relu(x + ctx @ wo_t^T + bo)
// grid (4, 256): n fastest for A-tile L2 reuse.
// ---------------------------------------------------------------------------
__global__ __launch_bounds__(256, 4) void gemm_out(
    const u16* __restrict__ ctx, const u16* __restrict__ wot,
    const float* __restrict__ x, const float* __restrict__ bo,
    float* __restrict__ out) {
  __shared__ u16 As[128 * 64];
  __shared__ u16 Bs[128 * 64];
  const int tid = threadIdx.x;
  const int wave = tid >> 6, lane = tid & 63;
  const int wm = wave & 1, wn = wave >> 1;
  const int lr = lane & 15, lg = lane >> 4;
  const int n0 = blockIdx.x * 128, m0 = blockIdx.y * 128;

  const f32x4 fz = {0.f, 0.f, 0.f, 0.f};
  f32x4 acc[4][4];
#pragma unroll
  for (int i = 0; i < 4; ++i)
#pragma unroll
    for (int j = 0; j < 4; ++j) acc[i][j] = fz;

  for (int kb = 0; kb < 512; kb += 64) {
#pragma unroll
    for (int j = 0; j < 4; ++j) {
      const int cb = (wave * 4 + j) * 64;
      const int c = cb + lane;
      const int r = c >> 3;
      const int cg = (c & 7) ^ (r & 7);  // XOR swizzle
      gl_lds16(&ctx[(size_t)(m0 + r) * 512 + kb + (cg << 3)], &As[cb * 8]);
      gl_lds16(&wot[(size_t)(n0 + r) * 512 + kb + (cg << 3)], &Bs[cb * 8]);
    }
    __syncthreads();
#pragma unroll
    for (int ks = 0; ks < 2; ++ks) {
      short8 af[4], bb[4];
#pragma unroll
      for (int i = 0; i < 4; ++i)
        af[i] = *reinterpret_cast<const short8*>(
            &As[(wm * 64 + i * 16 + lr) * 64 +
                (((ks * 4 + lg) ^ (lr & 7)) << 3)]);
#pragma unroll
      for (int j = 0; j < 4; ++j)
        bb[j] = *reinterpret_cast<const short8*>(
            &Bs[(wn * 64 + j * 16 + lr) * 64 +
                (((ks * 4 + lg) ^ (lr & 7)) << 3)]);
#pragma unroll
      for (int i = 0; i < 4; ++i)
#pragma unroll
        for (int j = 0; j < 4; ++j)
          acc[i][j] = __builtin_amdgcn_mfma_f32_16x16x32_bf16(
              af[i], bb[j], acc[i][j], 0, 0, 0);
    }
    __syncthreads();
  }
#pragma unroll
  for (int i = 0; i < 4; ++i) {
#pragma unroll
    for (int j = 0; j < 4; ++j) {
      const int col = n0 + wn * 64 + j * 16 + lr;
#pragma unroll
      for (int r = 0; r < 4; ++r) {
        const int row = m0 + wm * 64 + i * 16 + lg * 4 + r;
        float v = acc[i][j][r] + bo[col] + x[(size_t)row * 512 + col];
        out[(size_t)row * 512 + col] = fmaxf(v, 0.0f);
      }
    }
  }
}

// ---------------------------------------------------------------------------
extern "C" void kernel_launch(void* const* d_in, const int* in_sizes, int n_in,
                              void* d_out, int out_size, void* d_ws,
                              size_t ws_size, hipStream_t stream) {
  const float* x = (const float*)d_in[0];
  const float* wq = (const float*)d_in[1];
  const float* bq = (const float*)d_in[2];
  const float* wk = (const float*)d_in[3];
  const float* bk = (const float*)d_in[4];
  const float* wv = (const float*)d_in[5];
  const float* bv = (const float*)d_in[6];
  const float* wo = (const float*)d_in[7];
  const float* bo = (const float*)d_in[8];
  float* out = (float*)d_out;

  char* ws = (char*)d_ws;
  u16* qkv = (u16*)ws;                   // 32768*1536*2 = 100,663,296 B
  u16* ctx = (u16*)(ws + 100663296);     // 32768*512*2  =  33,554,432 B
  u16* xb = ctx;                         // xb overlaps ctx (dead before attn)
  u16* wqkv_t = (u16*)(ws + 134217728);  // 1,572,864 B
  u16* wo_t = (u16*)(ws + 135790592);    //   524,288 B  (total 136,314,880 B)

  hipLaunchKernelGGL(prep, dim3(20480), dim3(256), 0, stream, wq, wk, wv, wo,
                     x, wqkv_t, wo_t, xb);
  hipLaunchKernelGGL(gemm_qkv, dim3(12, 256), dim3(256), 0, stream, xb, wqkv_t,
                     bq, bk, bv, qkv);
  hipLaunchKernelGGL(attn, dim3(2048), dim3(256), 0, stream, qkv, ctx);
  hipLaunchKernelGGL(gemm_out, dim3(4, 256), dim3(256), 0, stream, ctx, wo_t,
                     x, bo, out);
}

// Round 7
// 277.913 us; speedup vs baseline: 1.1056x; 1.1056x over previous
//
#include <hip/hip_runtime.h>
#include <hip/hip_bf16.h>

typedef unsigned short u16;
typedef unsigned int u32;
typedef __attribute__((ext_vector_type(8))) short short8;
typedef __attribute__((ext_vector_type(4))) float f32x4;
typedef __attribute__((ext_vector_type(4))) _Float16 f16x4;

// fp32 -> bf16 round-to-nearest-even (finite inputs only)
static __device__ __forceinline__ u16 f2b(float f) {
  unsigned u = __builtin_bit_cast(unsigned, f);
  unsigned r = u + 0x7fffu + ((u >> 16) & 1u);
  return (u16)(r >> 16);
}
static __device__ __forceinline__ float b2f(u16 v) {
  return __builtin_bit_cast(float, (u32)v << 16);
}
static __device__ __forceinline__ unsigned pk2(float a, float b) {
  return (unsigned)f2b(a) | ((unsigned)f2b(b) << 16);
}
// two fp32 -> packed fp16 (RTZ pack instruction)
static __device__ __forceinline__ u32 pkh(float a, float b) {
  return __builtin_bit_cast(u32, __builtin_amdgcn_cvt_pkrtz(a, b));
}

// async 16B global -> LDS (wave-uniform LDS base + lane*16)
static __device__ __forceinline__ void gl_lds16(const u16* g, u16* l) {
  __builtin_amdgcn_global_load_lds(
      (const __attribute__((address_space(1))) unsigned*)g,
      (__attribute__((address_space(3))) unsigned*)l, 16, 0, 0);
}

// XOR-swizzle LDS layout (r5: conflicts 1.9e7 -> 0).
// XCD swizzle (r7): blocks sharing a reused tile are made consecutive on one
// XCD (xcd = blockIdx % 8 round-robin assumption) so the per-XCD L2 fetches
// the shared tile from HBM exactly once. r6 showed the naive grid transpose
// spreads sharers across 8 incoherent L2s (FETCH 86 -> 136 MB).

// ---------------------------------------------------------------------------
// Prep (merged): bf16 transposed weights (coalesced writes) + x fp32->bf16.
// ---------------------------------------------------------------------------
__global__ __launch_bounds__(256) void prep(
    const float* __restrict__ wq, const float* __restrict__ wk,
    const float* __restrict__ wv, const float* __restrict__ wo,
    const float* __restrict__ x, u16* __restrict__ wqkv_t,
    u16* __restrict__ wo_t, u16* __restrict__ xb) {
  int t = blockIdx.x * 256 + threadIdx.x;
  if (t < 786432) {
    int n = t >> 9, k = t & 511;  // write idx n*512+k, k fastest: coalesced
    const float* w = (n < 512) ? wq : (n < 1024 ? wk : wv);
    wqkv_t[(size_t)n * 512 + k] = f2b(w[k * 512 + (n & 511)]);
  } else if (t < 1048576) {
    int j = t - 786432;
    int n = j >> 9, k = j & 511;
    wo_t[(size_t)n * 512 + k] = f2b(wo[k * 512 + n]);
  } else {
    size_t i = (size_t)(t - 1048576) * 4;
    float4 v = *reinterpret_cast<const float4*>(&x[i]);
    uint2 p;
    p.x = pk2(v.x, v.y);
    p.y = pk2(v.z, v.w);
    *reinterpret_cast<uint2*>(&xb[i]) = p;
  }
}

// ---------------------------------------------------------------------------
// GEMM1: qkv[32768][1536] = xb[32768][512] @ wqkv_t^T + bias.
// Q cols pre-scaled by 0.125 (bf16), K cols bf16, V cols fp16.
// Grid 3072 1D, XCD-swizzled: 12 n-blocks of one m-tile consecutive per XCD.
// ---------------------------------------------------------------------------
__global__ __launch_bounds__(256, 4) void gemm_qkv(
    const u16* __restrict__ xb, const u16* __restrict__ wt,
    const float* __restrict__ bq, const float* __restrict__ bk,
    const float* __restrict__ bv, u16* __restrict__ qkv) {
  __shared__ u16 As[128 * 64];
  __shared__ u16 Bs[128 * 64];
  const int tid = threadIdx.x;
  const int wave = tid >> 6, lane = tid & 63;
  const int wm = wave & 1, wn = wave >> 1;
  const int lr = lane & 15, lg = lane >> 4;
  const int id = blockIdx.x;
  const int xcd = id & 7, s = id >> 3;     // s in [0,384)
  const int n0 = (s % 12) * 128;
  const int m0 = ((s / 12) * 8 + xcd) * 128;

  const f32x4 fz = {0.f, 0.f, 0.f, 0.f};
  f32x4 acc[4][4];
#pragma unroll
  for (int i = 0; i < 4; ++i)
#pragma unroll
    for (int j = 0; j < 4; ++j) acc[i][j] = fz;

  for (int kb = 0; kb < 512; kb += 64) {
#pragma unroll
    for (int j = 0; j < 4; ++j) {
      const int cb = (wave * 4 + j) * 64;
      const int c = cb + lane;
      const int r = c >> 3;
      const int cg = (c & 7) ^ (r & 7);  // XOR swizzle
      gl_lds16(&xb[(size_t)(m0 + r) * 512 + kb + (cg << 3)], &As[cb * 8]);
      gl_lds16(&wt[(size_t)(n0 + r) * 512 + kb + (cg << 3)], &Bs[cb * 8]);
    }
    __syncthreads();
#pragma unroll
    for (int ks = 0; ks < 2; ++ks) {
      short8 af[4], bb[4];
#pragma unroll
      for (int i = 0; i < 4; ++i)
        af[i] = *reinterpret_cast<const short8*>(
            &As[(wm * 64 + i * 16 + lr) * 64 +
                (((ks * 4 + lg) ^ (lr & 7)) << 3)]);
#pragma unroll
      for (int j = 0; j < 4; ++j)
        bb[j] = *reinterpret_cast<const short8*>(
            &Bs[(wn * 64 + j * 16 + lr) * 64 +
                (((ks * 4 + lg) ^ (lr & 7)) << 3)]);
#pragma unroll
      for (int i = 0; i < 4; ++i)
#pragma unroll
        for (int j = 0; j < 4; ++j)
          acc[i][j] = __builtin_amdgcn_mfma_f32_16x16x32_bf16(
              af[i], bb[j], acc[i][j], 0, 0, 0);
    }
    __syncthreads();
  }
#pragma unroll
  for (int i = 0; i < 4; ++i) {
    const int row0 = m0 + wm * 64 + i * 16 + lg * 4;
#pragma unroll
    for (int j = 0; j < 4; ++j) {
      const int col = n0 + wn * 64 + j * 16 + lr;
      const float bias =
          (col < 512) ? bq[col] : (col < 1024 ? bk[col - 512] : bv[col - 1024]);
#pragma unroll
      for (int r = 0; r < 4; ++r) {
        float v = acc[i][j][r] + bias;
        u16 ov;
        if (col < 512)
          ov = f2b(v * 0.125f);                       // Q: fold 1/sqrt(64)
        else if (col < 1024)
          ov = f2b(v);                                // K: bf16
        else
          ov = __builtin_bit_cast(u16, (_Float16)v);  // V: fp16
        qkv[(size_t)(row0 + r) * 1536 + col] = ov;
      }
    }
  }
}

// ---------------------------------------------------------------------------
// Flash attention. Block = (b, h, 128 q-rows), 4 waves x 32 q.
// S^T = K·Q^T (bf16 x32) -> exp in regs -> P^T in x16-f16 B-layout ->
// O^T = V^T·P^T (fp16 x16). Output written IN-PLACE over the Q-slots of qkv
// (each block overwrites exactly the Q region it alone reads).
// XCD-swizzled: the 4 q-tiles of one (b,h) are consecutive on one XCD.
// ---------------------------------------------------------------------------
__global__ __launch_bounds__(256, 3) void attn(u16* __restrict__ qkv) {
  __shared__ u16 QOs[128 * 66];     // Q (swizzled stride 64) / O^T (stride 66)
  __shared__ u16 Ks[2][64 * 64];    // bf16, async, XOR-swizzled
  __shared__ u16 VsT[2][64 * 70];   // fp16, VsT[d][t], stride 70

  const int tid = threadIdx.x;
  const int wave = tid >> 6, lane = tid & 63;
  const int lr = lane & 15, lg = lane >> 4;
  const int bx = blockIdx.x;
  const int xcd = bx & 7, s = bx >> 3;  // s in [0,256)
  const int q0 = (s & 3) * 128;
  const int bh = (s >> 2) * 8 + xcd;    // [0,512), 4 q-tiles consecutive/XCD
  const int b = bh >> 3, h = bh & 7;
  const size_t rowbase = (size_t)b * 512;

  // async-load Q tile (128 x 64, swizzled)
#pragma unroll
  for (int j = 0; j < 4; ++j) {
    const int cb = (wave * 4 + j) * 64, c = cb + lane;
    const int r = c >> 3, cg = (c & 7) ^ (r & 7);
    gl_lds16(&qkv[(rowbase + q0 + r) * 1536 + h * 64 + (cg << 3)],
             &QOs[cb * 8]);
  }
  // async-load K tile 0 (swizzled)
#pragma unroll
  for (int j = 0; j < 2; ++j) {
    const int cb = (wave * 2 + j) * 64, c = cb + lane;
    const int r = c >> 3, cg = (c & 7) ^ (r & 7);
    gl_lds16(&qkv[(rowbase + r) * 1536 + 512 + h * 64 + (cg << 3)],
             &Ks[0][cb * 8]);
  }
  // V tile 0: regs -> transposed LDS
  uint4 vreg[2];
#pragma unroll
  for (int i = 0; i < 2; ++i) {
    int idx = tid + i * 256, r = idx >> 3, cg = idx & 7;
    vreg[i] = *reinterpret_cast<const uint4*>(
        &qkv[(rowbase + r) * 1536 + 1024 + h * 64 + cg * 8]);
  }
#pragma unroll
  for (int i = 0; i < 2; ++i) {
    int idx = tid + i * 256, r = idx >> 3, cg = idx & 7;
    const u16* pv = reinterpret_cast<const u16*>(&vreg[i]);
#pragma unroll
    for (int jj = 0; jj < 8; ++jj) VsT[0][(cg * 8 + jj) * 70 + r] = pv[jj];
  }
  __syncthreads();

  // Q fragments (B-operand of S^T mfma); QOs dead until epilogue
  short8 aq[2][2];
#pragma unroll
  for (int g = 0; g < 2; ++g)
#pragma unroll
    for (int ks = 0; ks < 2; ++ks)
      aq[g][ks] = *reinterpret_cast<const short8*>(
          &QOs[(wave * 32 + g * 16 + lr) * 64 +
               (((ks * 4 + lg) ^ (lr & 7)) << 3)]);

  const f32x4 fz = {0.f, 0.f, 0.f, 0.f};
  f32x4 oacc[2][4];
#pragma unroll
  for (int g = 0; g < 2; ++g)
#pragma unroll
    for (int dt = 0; dt < 4; ++dt) oacc[g][dt] = fz;
  float lsum[2] = {0.f, 0.f};

  for (int tt = 0; tt < 8; ++tt) {
    const int buf = tt & 1;
    if (tt < 7) {  // prefetch K/V for tile tt+1
#pragma unroll
      for (int j = 0; j < 2; ++j) {
        const int cb = (wave * 2 + j) * 64, c = cb + lane;
        const int r = c >> 3, cg = (c & 7) ^ (r & 7);
        gl_lds16(&qkv[(rowbase + (tt + 1) * 64 + r) * 1536 + 512 + h * 64 +
                      (cg << 3)],
                 &Ks[buf ^ 1][cb * 8]);
      }
#pragma unroll
      for (int i = 0; i < 2; ++i) {
        int idx = tid + i * 256, r = idx >> 3, cg = idx & 7;
        vreg[i] = *reinterpret_cast<const uint4*>(
            &qkv[(rowbase + (tt + 1) * 64 + r) * 1536 + 1024 + h * 64 + cg * 8]);
      }
    }

    // S^T = K·Q^T : st[g][mt] covers t = mt*16+lg*4+r, q = lr
    f32x4 st[2][4];
#pragma unroll
    for (int g = 0; g < 2; ++g)
#pragma unroll
      for (int mt = 0; mt < 4; ++mt) st[g][mt] = fz;
#pragma unroll
    for (int mt = 0; mt < 4; ++mt) {
      short8 k0 = *reinterpret_cast<const short8*>(
          &Ks[buf][(mt * 16 + lr) * 64 + ((lg ^ (lr & 7)) << 3)]);
      short8 k1 = *reinterpret_cast<const short8*>(
          &Ks[buf][(mt * 16 + lr) * 64 + (((4 + lg) ^ (lr & 7)) << 3)]);
#pragma unroll
      for (int g = 0; g < 2; ++g) {
        st[g][mt] = __builtin_amdgcn_mfma_f32_16x16x32_bf16(k0, aq[g][0],
                                                            st[g][mt], 0, 0, 0);
        st[g][mt] = __builtin_amdgcn_mfma_f32_16x16x32_bf16(k1, aq[g][1],
                                                            st[g][mt], 0, 0, 0);
      }
    }

    // exp (Q pre-scaled), partial l, pack P^T straight into x16 B-layout
    f16x4 pfrag[2][4];
#pragma unroll
    for (int g = 0; g < 2; ++g)
#pragma unroll
      for (int mt = 0; mt < 4; ++mt) {
        float e0 = __expf(st[g][mt][0]), e1 = __expf(st[g][mt][1]);
        float e2 = __expf(st[g][mt][2]), e3 = __expf(st[g][mt][3]);
        lsum[g] += (e0 + e1) + (e2 + e3);
        uint2 uu;
        uu.x = pkh(e0, e1);
        uu.y = pkh(e2, e3);
        pfrag[g][mt] = __builtin_bit_cast(f16x4, uu);
      }

    // O^T += V^T · P^T  (x16 f16 MFMA; A-frag from VsT, B-frag = pfrag)
#pragma unroll
    for (int dt = 0; dt < 4; ++dt) {
#pragma unroll
      for (int tw = 0; tw < 4; ++tw) {
        const int a0 = (dt * 16 + lr) * 70 + tw * 16 + lg * 4;
        uint2 uu;
        uu.x = *reinterpret_cast<const u32*>(&VsT[buf][a0]);
        uu.y = *reinterpret_cast<const u32*>(&VsT[buf][a0 + 2]);
        f16x4 vf = __builtin_bit_cast(f16x4, uu);
#pragma unroll
        for (int g = 0; g < 2; ++g)
          oacc[g][dt] = __builtin_amdgcn_mfma_f32_16x16x16f16(
              vf, pfrag[g][tw], oacc[g][dt], 0, 0, 0);
      }
    }

    if (tt < 7) {  // write prefetched V^T into the other buffer
#pragma unroll
      for (int i = 0; i < 2; ++i) {
        int idx = tid + i * 256, r = idx >> 3, cg = idx & 7;
        const u16* pv = reinterpret_cast<const u16*>(&vreg[i]);
#pragma unroll
        for (int jj = 0; jj < 8; ++jj)
          VsT[buf ^ 1][(cg * 8 + jj) * 70 + r] = pv[jj];
      }
    }
    __syncthreads();
  }

  // reduce l over the 4 lane-groups holding each q, normalize
#pragma unroll
  for (int g = 0; g < 2; ++g) {
    float s2 = lsum[g];
    s2 += __shfl_xor(s2, 16);
    s2 += __shfl_xor(s2, 32);
    lsum[g] = 1.0f / s2;
  }
  // O^T -> O via LDS (u32-granular, stride 66), then coalesced stores into
  // the Q-slots of qkv (in-place ctx).
#pragma unroll
  for (int g = 0; g < 2; ++g)
#pragma unroll
    for (int dt = 0; dt < 4; ++dt) {
      f32x4 o = oacc[g][dt];
      const float li = lsum[g];
      const int base = (wave * 32 + g * 16 + lr) * 66 + dt * 16 + lg * 4;
      *reinterpret_cast<u32*>(&QOs[base]) = pk2(o[0] * li, o[1] * li);
      *reinterpret_cast<u32*>(&QOs[base + 2]) = pk2(o[2] * li, o[3] * li);
    }
  __syncthreads();
#pragma unroll
  for (int i = 0; i < 4; ++i) {
    int idx = tid + i * 256, r = idx >> 3, cg = idx & 7;
    const u16* src = &QOs[r * 66 + cg * 8];
    uint4 w;
    w.x = *reinterpret_cast<const u32*>(&src[0]);
    w.y = *reinterpret_cast<const u32*>(&src[2]);
    w.z = *reinterpret_cast<const u32*>(&src[4]);
    w.w = *reinterpret_cast<const u32*>(&src[6]);
    *reinterpret_cast<uint4*>(
        &qkv[(rowbase + q0 + r) * 1536 + h * 64 + cg * 8]) = w;
  }
}

// ---------------------------------------------------------------------------
// GEMM2: out[32768][512] fp32 = relu(xb + ctx @ wo_t^T + bo)
// ctx lives in the Q-slots of qkv (row stride 1536). Residual from xb (bf16).
// XCD-swizzled grid 1024: 4 n-blocks of one m-tile consecutive per XCD.
// ---------------------------------------------------------------------------
__global__ __launch_bounds__(256, 4) void gemm_out(
    const u16* __restrict__ ctxq, const u16* __restrict__ wot,
    const u16* __restrict__ xb, const float* __restrict__ bo,
    float* __restrict__ out) {
  __shared__ u16 As[128 * 64];
  __shared__ u16 Bs[128 * 64];
  const int tid = threadIdx.x;
  const int wave = tid >> 6, lane = tid & 63;
  const int wm = wave & 1, wn = wave >> 1;
  const int lr = lane & 15, lg = lane >> 4;
  const int id = blockIdx.x;
  const int xcd = id & 7, s = id >> 3;  // s in [0,128)
  const int n0 = (s & 3) * 128;
  const int m0 = ((s >> 2) * 8 + xcd) * 128;

  const f32x4 fz = {0.f, 0.f, 0.f, 0.f};
  f32x4 acc[4][4];
#pragma unroll
  for (int i = 0; i < 4; ++i)
#pragma unroll
    for (int j = 0; j < 4; ++j) acc[i][j] = fz;

  for (int kb = 0; kb < 512; kb += 64) {
#pragma unroll
    for (int j = 0; j < 4; ++j) {
      const int cb = (wave * 4 + j) * 64;
      const int c = cb + lane;
      const int r = c >> 3;
      const int cg = (c & 7) ^ (r & 7);  // XOR swizzle
      gl_lds16(&ctxq[(size_t)(m0 + r) * 1536 + kb + (cg << 3)], &As[cb * 8]);
      gl_lds16(&wot[(size_t)(n0 + r) * 512 + kb + (cg << 3)], &Bs[cb * 8]);
    }
    __syncthreads();
#pragma unroll
    for (int ks = 0; ks < 2; ++ks) {
      short8 af[4], bb[4];
#pragma unroll
      for (int i = 0; i < 4; ++i)
        af[i] = *reinterpret_cast<const short8*>(
            &As[(wm * 64 + i * 16 + lr) * 64 +
                (((ks * 4 + lg) ^ (lr & 7)) << 3)]);
#pragma unroll
      for (int j = 0; j < 4; ++j)
        bb[j] = *reinterpret_cast<const short8*>(
            &Bs[(wn * 64 + j * 16 + lr) * 64 +
                (((ks * 4 + lg) ^ (lr & 7)) << 3)]);
#pragma unroll
      for (int i = 0; i < 4; ++i)
#pragma unroll
        for (int j = 0; j < 4; ++j)
          acc[i][j] = __builtin_amdgcn_mfma_f32_16x16x32_bf16(
              af[i], bb[j], acc[i][j], 0, 0, 0);
    }
    __syncthreads();
  }
#pragma unroll
  for (int i = 0; i < 4; ++i) {
#pragma unroll
    for (int j = 0; j < 4; ++j) {
      const int col = n0 + wn * 64 + j * 16 + lr;
#pragma unroll
      for (int r = 0; r < 4; ++r) {
        const int row = m0 + wm * 64 + i * 16 + lg * 4 + r;
        float v = acc[i][j][r] + bo[col] + b2f(xb[(size_t)row * 512 + col]);
        out[(size_t)row * 512 + col] = fmaxf(v, 0.0f);
      }
    }
  }
}

// ---------------------------------------------------------------------------
extern "C" void kernel_launch(void* const* d_in, const int* in_sizes, int n_in,
                              void* d_out, int out_size, void* d_ws,
                              size_t ws_size, hipStream_t stream) {
  const float* x = (const float*)d_in[0];
  const float* wq = (const float*)d_in[1];
  const float* bq = (const float*)d_in[2];
  const float* wk = (const float*)d_in[3];
  const float* bk = (const float*)d_in[4];
  const float* wv = (const float*)d_in[5];
  const float* bv = (const float*)d_in[6];
  const float* wo = (const float*)d_in[7];
  const float* bo = (const float*)d_in[8];
  float* out = (float*)d_out;

  char* ws = (char*)d_ws;
  u16* qkv = (u16*)ws;                   // 32768*1536*2 = 100,663,296 B
                                         //   (Q-slots become ctx after attn)
  u16* xb = (u16*)(ws + 100663296);      // 32768*512*2  =  33,554,432 B
  u16* wqkv_t = (u16*)(ws + 134217728);  // 1,572,864 B
  u16* wo_t = (u16*)(ws + 135790592);    //   524,288 B  (total 136,314,880 B)

  hipLaunchKernelGGL(prep, dim3(20480), dim3(256), 0, stream, wq, wk, wv, wo,
                     x, wqkv_t, wo_t, xb);
  hipLaunchKernelGGL(gemm_qkv, dim3(3072), dim3(256), 0, stream, xb, wqkv_t,
                     bq, bk, bv, qkv);
  hipLaunchKernelGGL(attn, dim3(2048), dim3(256), 0, stream, qkv);
  hipLaunchKernelGGL(gemm_out, dim3(1024), dim3(256), 0, stream, qkv, wo_t,
                     xb, bo, out);
}